// Round 1
// baseline (4137.453 us; speedup 1.0000x reference)
//
#include <hip/hip_runtime.h>
#include <hip/hip_bf16.h>

// GCN 3-layer: h = relu(S (X W) + b), S = D^-1/2 (A + I) D^-1/2 applied as
//   hs = (X@W) * d_inv[row]    (GEMM epilogue, also initializes acc = hs -> self loop)
//   acc[dst] += hs[src]        (edge scatter, atomics)
//   out = act(d_inv[row]*acc + b)

constexpr int BLK = 256;

// ---------- degree ----------
__global__ void deg_init(float* deg, int n) {
    int i = blockIdx.x * BLK + threadIdx.x;
    if (i < n) deg[i] = 1.0f;   // self-loop
}

__global__ void deg_count(const int* __restrict__ dst, float* deg, int E) {
    int e = blockIdx.x * BLK + threadIdx.x;
    if (e < E) atomicAdd(&deg[dst[e]], 1.0f);
}

__global__ void deg_rsqrt(float* deg, int n) {
    int i = blockIdx.x * BLK + threadIdx.x;
    if (i < n) deg[i] = rsqrtf(deg[i]);
}

// ---------- GEMM: hs = (X @ W) * d_inv[row]; acc = hs ----------
// Block computes 64 rows x 64 cols (cols padded to 64, guarded store for NOUT<64).
template<int K, int NOUT>
__global__ __launch_bounds__(256) void gemm_scale(
    const float* __restrict__ X, const float* __restrict__ W,
    const float* __restrict__ d_inv,
    float* __restrict__ hs, float* __restrict__ acc, int M)
{
    __shared__ float Wl[K * 64];
    __shared__ float Xl[64][17];          // +1 pad vs 16 -> no pow2 bank stride

    int t = threadIdx.x;
    for (int idx = t; idx < K * 64; idx += 256) {
        int k = idx >> 6, c = idx & 63;
        Wl[idx] = (c < NOUT) ? W[k * NOUT + c] : 0.0f;
    }

    int row0 = blockIdx.x * 64;
    int tr = t >> 4, tc = t & 15;         // 16x16 threads, each 4x4 outputs
    float a[4][4] = {};

    for (int k0 = 0; k0 < K; k0 += 16) {
        __syncthreads();                  // protect Xl (and Wl on iter 0)
        int r = t >> 2, q = t & 3;        // 64 rows x 4 float4 loaders
        int grow = row0 + r;
        float4 xv = make_float4(0.f, 0.f, 0.f, 0.f);
        if (grow < M) xv = *(const float4*)(X + (size_t)grow * K + k0 + q * 4);
        Xl[r][q * 4 + 0] = xv.x; Xl[r][q * 4 + 1] = xv.y;
        Xl[r][q * 4 + 2] = xv.z; Xl[r][q * 4 + 3] = xv.w;
        __syncthreads();

#pragma unroll
        for (int kk = 0; kk < 16; ++kk) {
            float xr[4], wr[4];
#pragma unroll
            for (int i = 0; i < 4; ++i) xr[i] = Xl[tr * 4 + i][kk];
#pragma unroll
            for (int j = 0; j < 4; ++j) wr[j] = Wl[(k0 + kk) * 64 + tc * 4 + j];
#pragma unroll
            for (int i = 0; i < 4; ++i)
#pragma unroll
                for (int j = 0; j < 4; ++j)
                    a[i][j] += xr[i] * wr[j];
        }
    }

#pragma unroll
    for (int i = 0; i < 4; ++i) {
        int r = row0 + tr * 4 + i;
        if (r < M) {
            float s = d_inv[r];
#pragma unroll
            for (int j = 0; j < 4; ++j) {
                int c = tc * 4 + j;
                if (c < NOUT) {
                    float v = a[i][j] * s;
                    hs [(size_t)r * NOUT + c] = v;
                    acc[(size_t)r * NOUT + c] = v;   // self-loop init
                }
            }
        }
    }
}

// ---------- edge scatter: acc[dst] += hs[src], float4 per thread ----------
template<int D>
__global__ __launch_bounds__(256) void edge_agg(
    const float* __restrict__ hs, float* __restrict__ acc,
    const int* __restrict__ src, const int* __restrict__ dst, int E)
{
    constexpr int Q = D / 4;              // float4 groups per edge
    int idx = blockIdx.x * BLK + threadIdx.x;
    int e = idx / Q;
    int q = idx - e * Q;
    if (e < E) {
        int s = src[e], d = dst[e];
        const float4 v = *(const float4*)(hs + (size_t)s * D + q * 4);
        float* p = acc + (size_t)d * D + q * 4;
        atomicAdd(p + 0, v.x);
        atomicAdd(p + 1, v.y);
        atomicAdd(p + 2, v.z);
        atomicAdd(p + 3, v.w);
    }
}

// ---------- epilogue: out = act(d_inv[i]*acc + b[d]) ----------
template<int D, bool RELU>
__global__ void finish_kernel(
    const float* __restrict__ acc, const float* __restrict__ b,
    const float* __restrict__ d_inv, float* __restrict__ out, int n)
{
    int idx = blockIdx.x * BLK + threadIdx.x;
    if (idx < n * D) {
        int i = idx / D;
        int d = idx - i * D;
        float v = d_inv[i] * acc[idx] + b[d];
        if (RELU) v = fmaxf(v, 0.0f);
        out[idx] = v;
    }
}

extern "C" void kernel_launch(void* const* d_in, const int* in_sizes, int n_in,
                              void* d_out, int out_size, void* d_ws, size_t ws_size,
                              hipStream_t stream) {
    const float* x   = (const float*)d_in[0];
    const int*   ei  = (const int*)  d_in[1];
    const float* W1  = (const float*)d_in[2];
    const float* bb1 = (const float*)d_in[3];
    const float* W2  = (const float*)d_in[4];
    const float* bb2 = (const float*)d_in[5];
    const float* W3  = (const float*)d_in[6];
    const float* bb3 = (const float*)d_in[7];
    float* out = (float*)d_out;

    const int N = in_sizes[0] / 128;      // 100000
    const int E = in_sizes[1] / 2;        // 1600000
    const int* src = ei;
    const int* dst = ei + E;

    // workspace layout (floats)
    float* ws   = (float*)d_ws;
    const size_t NP  = ((size_t)N + 255) & ~255ull;  // padded N
    const size_t N64 = (size_t)N * 64;
    float* dinv = ws;                 // NP floats (deg -> d_inv in place)
    float* bufH = ws + NP;            // hs     : N*64
    float* bufA = bufH + N64;         // acc    : N*64
    float* bufO = bufA + N64;         // layer output : N*64

    dim3 blk(BLK);
    int gN    = (N + BLK - 1) / BLK;
    int gE    = (E + BLK - 1) / BLK;
    int gRows = (N + 63) / 64;

    // degrees
    deg_init <<<gN, blk, 0, stream>>>(dinv, N);
    deg_count<<<gE, blk, 0, stream>>>(dst, dinv, E);
    deg_rsqrt<<<gN, blk, 0, stream>>>(dinv, N);

    // ---- layer 1: 128 -> 64, relu ----
    gemm_scale<128, 64><<<gRows, blk, 0, stream>>>(x, W1, dinv, bufH, bufA, N);
    {
        int total = E * 16;               // E * (64/4)
        edge_agg<64><<<(total + BLK - 1) / BLK, blk, 0, stream>>>(bufH, bufA, src, dst, E);
    }
    finish_kernel<64, true><<<(N * 64 + BLK - 1) / BLK, blk, 0, stream>>>(bufA, bb1, dinv, bufO, N);

    // ---- layer 2: 64 -> 64, relu ----
    gemm_scale<64, 64><<<gRows, blk, 0, stream>>>(bufO, W2, dinv, bufH, bufA, N);
    {
        int total = E * 16;
        edge_agg<64><<<(total + BLK - 1) / BLK, blk, 0, stream>>>(bufH, bufA, src, dst, E);
    }
    finish_kernel<64, true><<<(N * 64 + BLK - 1) / BLK, blk, 0, stream>>>(bufA, bb2, dinv, bufO, N);

    // ---- layer 3: 64 -> 40, no relu, to d_out ----
    gemm_scale<64, 40><<<gRows, blk, 0, stream>>>(bufO, W3, dinv, bufH, bufA, N);
    {
        int total = E * 10;               // E * (40/4) with 40-dim rows
        edge_agg<40><<<(total + BLK - 1) / BLK, blk, 0, stream>>>(bufH, bufA, src, dst, E);
    }
    finish_kernel<40, false><<<(N * 40 + BLK - 1) / BLK, blk, 0, stream>>>(bufA, bb3, dinv, out, N);
}

// Round 2
// 786.643 us; speedup vs baseline: 5.2596x; 5.2596x over previous
//
#include <hip/hip_runtime.h>
#include <hip/hip_bf16.h>

// GCN 3-layer, CSR-based aggregation (no float atomics):
//   cnt   = histogram(dst)            -> d_inv = rsqrt(cnt+1)
//   row_ptr = exclusive_scan(cnt)     -> csr_src = edges grouped by dst
//   hs    = (X@W) * d_inv[row]        (GEMM epilogue)
//   out_i = act(d_inv[i] * (hs_i + sum_{e:dst=i} hs[src_e]) + b)  (one wave/node)

constexpr int BLK = 256;

// ---------- utility ----------
__global__ void zero_int(int* p, int n) {
    int i = blockIdx.x * BLK + threadIdx.x;
    if (i < n) p[i] = 0;
}

__global__ void hist_dst(const int* __restrict__ dst, int* __restrict__ cnt, int E) {
    int e = blockIdx.x * BLK + threadIdx.x;
    if (e < E) atomicAdd(&cnt[dst[e]], 1);
}

__global__ void dinv_from_cnt(const int* __restrict__ cnt, float* __restrict__ dinv, int n) {
    int i = blockIdx.x * BLK + threadIdx.x;
    if (i < n) dinv[i] = rsqrtf((float)cnt[i] + 1.0f);   // +1 self-loop
}

// ---------- exclusive scan (3 kernels, chunk = 1024 elements) ----------
__global__ void scan_chunks(const int* __restrict__ cnt, int* __restrict__ excl,
                            int* __restrict__ csums, int n) {
    __shared__ int sh[256];
    int t = threadIdx.x;
    int base = blockIdx.x * 1024;
    int v[4]; int s = 0;
#pragma unroll
    for (int j = 0; j < 4; ++j) {
        int idx = base + t * 4 + j;
        v[j] = (idx < n) ? cnt[idx] : 0;
        s += v[j];
    }
    sh[t] = s;
    __syncthreads();
    for (int off = 1; off < 256; off <<= 1) {
        int x = (t >= off) ? sh[t - off] : 0;
        __syncthreads();
        sh[t] += x;
        __syncthreads();
    }
    int run = sh[t] - s;                      // exclusive prefix of this thread's group
    if (t == 255) csums[blockIdx.x] = sh[255];
#pragma unroll
    for (int j = 0; j < 4; ++j) {
        int idx = base + t * 4 + j;
        if (idx < n) excl[idx] = run;
        run += v[j];
    }
}

__global__ void scan_sums(int* __restrict__ csums, int nChunks) {  // nChunks <= 256
    __shared__ int sh[256];
    int t = threadIdx.x;
    int v = (t < nChunks) ? csums[t] : 0;
    sh[t] = v;
    __syncthreads();
    for (int off = 1; off < 256; off <<= 1) {
        int x = (t >= off) ? sh[t - off] : 0;
        __syncthreads();
        sh[t] += x;
        __syncthreads();
    }
    if (t < nChunks) csums[t] = sh[t] - v;    // exclusive
}

__global__ void scan_add(int* __restrict__ row_ptr, const int* __restrict__ csums,
                         int n, int E) {
    int idx = blockIdx.x * BLK + threadIdx.x;
    if (idx < n) row_ptr[idx] += csums[idx >> 10];
    if (idx == 0) row_ptr[n] = E;
}

// ---------- scatter edges into dst-grouped order ----------
__global__ void scatter_csr(const int* __restrict__ src, const int* __restrict__ dst,
                            const int* __restrict__ row_ptr, int* __restrict__ wcnt,
                            int* __restrict__ csr, int E) {
    int e = blockIdx.x * BLK + threadIdx.x;
    if (e < E) {
        int d = dst[e];
        int p = row_ptr[d] + atomicAdd(&wcnt[d], 1);
        csr[p] = src[e];
    }
}

// ---------- GEMM: hs = (X @ W) * d_inv[row] ----------
template<int K, int NOUT>
__global__ __launch_bounds__(256) void gemm_scale(
    const float* __restrict__ X, const float* __restrict__ W,
    const float* __restrict__ d_inv, float* __restrict__ hs, int M)
{
    __shared__ float Wl[K * 64];
    __shared__ float Xl[64][17];

    int t = threadIdx.x;
    for (int idx = t; idx < K * 64; idx += 256) {
        int k = idx >> 6, c = idx & 63;
        Wl[idx] = (c < NOUT) ? W[k * NOUT + c] : 0.0f;
    }

    int row0 = blockIdx.x * 64;
    int tr = t >> 4, tc = t & 15;
    float a[4][4] = {};

    for (int k0 = 0; k0 < K; k0 += 16) {
        __syncthreads();
        int r = t >> 2, q = t & 3;
        int grow = row0 + r;
        float4 xv = make_float4(0.f, 0.f, 0.f, 0.f);
        if (grow < M) xv = *(const float4*)(X + (size_t)grow * K + k0 + q * 4);
        Xl[r][q * 4 + 0] = xv.x; Xl[r][q * 4 + 1] = xv.y;
        Xl[r][q * 4 + 2] = xv.z; Xl[r][q * 4 + 3] = xv.w;
        __syncthreads();

#pragma unroll
        for (int kk = 0; kk < 16; ++kk) {
            float xr[4], wr[4];
#pragma unroll
            for (int i = 0; i < 4; ++i) xr[i] = Xl[tr * 4 + i][kk];
#pragma unroll
            for (int j = 0; j < 4; ++j) wr[j] = Wl[(k0 + kk) * 64 + tc * 4 + j];
#pragma unroll
            for (int i = 0; i < 4; ++i)
#pragma unroll
                for (int j = 0; j < 4; ++j)
                    a[i][j] += xr[i] * wr[j];
        }
    }

#pragma unroll
    for (int i = 0; i < 4; ++i) {
        int r = row0 + tr * 4 + i;
        if (r < M) {
            float s = d_inv[r];
#pragma unroll
            for (int j = 0; j < 4; ++j) {
                int c = tc * 4 + j;
                if (c < NOUT) hs[(size_t)r * NOUT + c] = a[i][j] * s;
            }
        }
    }
}

// ---------- fused aggregate + epilogue: one wave per node, lane = dim ----------
template<int D, bool RELU>
__global__ __launch_bounds__(256) void agg_fused(
    const float* __restrict__ hs, const int* __restrict__ row_ptr,
    const int* __restrict__ csr, const float* __restrict__ dinv,
    const float* __restrict__ b, float* __restrict__ out, int N)
{
    int wave = (blockIdx.x * 256 + threadIdx.x) >> 6;
    int lane = threadIdx.x & 63;
    if (wave >= N) return;
    int i = wave;
    int beg = row_ptr[i], end = row_ptr[i + 1];

    float acc = 0.0f;
    if (lane < D) acc = hs[(size_t)i * D + lane];          // self-loop term

    for (int c = beg; c < end; c += 64) {
        int m = end - c; if (m > 64) m = 64;
        int s_l = (lane < m) ? csr[c + lane] : 0;          // coalesced src prefetch
        for (int k = 0; k < m; ++k) {
            int s = __shfl(s_l, k, 64);
            if (lane < D) acc += hs[(size_t)s * D + lane]; // coalesced 256B row read
        }
    }

    if (lane < D) {
        float v = dinv[i] * acc + b[lane];
        if (RELU) v = fmaxf(v, 0.0f);
        out[(size_t)i * D + lane] = v;
    }
}

extern "C" void kernel_launch(void* const* d_in, const int* in_sizes, int n_in,
                              void* d_out, int out_size, void* d_ws, size_t ws_size,
                              hipStream_t stream) {
    const float* x   = (const float*)d_in[0];
    const int*   ei  = (const int*)  d_in[1];
    const float* W1  = (const float*)d_in[2];
    const float* bb1 = (const float*)d_in[3];
    const float* W2  = (const float*)d_in[4];
    const float* bb2 = (const float*)d_in[5];
    const float* W3  = (const float*)d_in[6];
    const float* bb3 = (const float*)d_in[7];
    float* out = (float*)d_out;

    const int N = in_sizes[0] / 128;      // 100000
    const int E = in_sizes[1] / 2;        // 1600000
    const int* src = ei;
    const int* dst = ei + E;

    // workspace layout (4-byte units)
    float* ws = (float*)d_ws;
    const size_t NP  = ((size_t)N + 255) & ~255ull;
    const size_t N64 = (size_t)N * 64;
    float* dinv = ws;                        // NP
    float* bufH = ws + NP;                   // N*64  (hs)
    float* bufO = bufH + N64;                // N*64  (layer activations)
    int*   row_ptr = (int*)(bufO + N64);     // N+1
    int*   cnt     = row_ptr + (N + 1);      // N  (histogram, then scatter counters)
    int*   csums   = cnt + N;                // 256
    int*   csr     = csums + 256;            // E

    dim3 blk(BLK);
    int gN = (N + BLK - 1) / BLK;
    int gE = (E + BLK - 1) / BLK;
    int gRows = (N + 63) / 64;
    int gWave = (N * 64 + BLK - 1) / BLK;    // one wave per node
    int nChunks = (N + 1023) / 1024;         // 98 (<=256 required)

    // ---- CSR build + degrees ----
    zero_int<<<gN, blk, 0, stream>>>(cnt, N);
    hist_dst<<<gE, blk, 0, stream>>>(dst, cnt, E);
    dinv_from_cnt<<<gN, blk, 0, stream>>>(cnt, dinv, N);
    scan_chunks<<<nChunks, blk, 0, stream>>>(cnt, row_ptr, csums, N);
    scan_sums<<<1, blk, 0, stream>>>(csums, nChunks);
    scan_add<<<gN, blk, 0, stream>>>(row_ptr, csums, N, E);
    zero_int<<<gN, blk, 0, stream>>>(cnt, N);
    scatter_csr<<<gE, blk, 0, stream>>>(src, dst, row_ptr, cnt, csr, E);

    // ---- layer 1: 128 -> 64, relu ----
    gemm_scale<128, 64><<<gRows, blk, 0, stream>>>(x, W1, dinv, bufH, N);
    agg_fused<64, true><<<gWave, blk, 0, stream>>>(bufH, row_ptr, csr, dinv, bb1, bufO, N);

    // ---- layer 2: 64 -> 64, relu ----
    gemm_scale<64, 64><<<gRows, blk, 0, stream>>>(bufO, W2, dinv, bufH, N);
    agg_fused<64, true><<<gWave, blk, 0, stream>>>(bufH, row_ptr, csr, dinv, bb2, bufO, N);

    // ---- layer 3: 64 -> 40, no relu ----
    gemm_scale<64, 40><<<gRows, blk, 0, stream>>>(bufO, W3, dinv, bufH, N);
    agg_fused<40, false><<<gWave, blk, 0, stream>>>(bufH, row_ptr, csr, dinv, bb3, out, N);
}

// Round 3
// 515.616 us; speedup vs baseline: 8.0243x; 1.5256x over previous
//
#include <hip/hip_runtime.h>
#include <hip/hip_bf16.h>

// GCN 3-layer, CSR aggregation, no float atomics.
//   hs = (X@W) * d_inv[row]   (tiled fp32 GEMM, float4 LDS reads, no spill)
//   out_i = act(d_inv[i]*(hs_i + sum_{e:dst=i} hs[src_e]) + b)
//     (one wave/node; 16 lanes x float4, 4 edges in flight, shfl_xor reduce)

constexpr int BLK = 256;

// ---------- utility ----------
__global__ void zero_int(int* p, int n) {
    int i = blockIdx.x * BLK + threadIdx.x;
    if (i < n) p[i] = 0;
}

__global__ void hist_dst(const int* __restrict__ dst, int* __restrict__ cnt, int E) {
    int e = blockIdx.x * BLK + threadIdx.x;
    if (e < E) atomicAdd(&cnt[dst[e]], 1);
}

__global__ void dinv_from_cnt(const int* __restrict__ cnt, float* __restrict__ dinv, int n) {
    int i = blockIdx.x * BLK + threadIdx.x;
    if (i < n) dinv[i] = rsqrtf((float)cnt[i] + 1.0f);   // +1 self-loop
}

// ---------- exclusive scan (3 kernels, chunk = 1024 elements) ----------
__global__ void scan_chunks(const int* __restrict__ cnt, int* __restrict__ excl,
                            int* __restrict__ csums, int n) {
    __shared__ int sh[256];
    int t = threadIdx.x;
    int base = blockIdx.x * 1024;
    int v[4]; int s = 0;
#pragma unroll
    for (int j = 0; j < 4; ++j) {
        int idx = base + t * 4 + j;
        v[j] = (idx < n) ? cnt[idx] : 0;
        s += v[j];
    }
    sh[t] = s;
    __syncthreads();
    for (int off = 1; off < 256; off <<= 1) {
        int x = (t >= off) ? sh[t - off] : 0;
        __syncthreads();
        sh[t] += x;
        __syncthreads();
    }
    int run = sh[t] - s;
    if (t == 255) csums[blockIdx.x] = sh[255];
#pragma unroll
    for (int j = 0; j < 4; ++j) {
        int idx = base + t * 4 + j;
        if (idx < n) excl[idx] = run;
        run += v[j];
    }
}

__global__ void scan_sums(int* __restrict__ csums, int nChunks) {  // nChunks <= 256
    __shared__ int sh[256];
    int t = threadIdx.x;
    int v = (t < nChunks) ? csums[t] : 0;
    sh[t] = v;
    __syncthreads();
    for (int off = 1; off < 256; off <<= 1) {
        int x = (t >= off) ? sh[t - off] : 0;
        __syncthreads();
        sh[t] += x;
        __syncthreads();
    }
    if (t < nChunks) csums[t] = sh[t] - v;
}

__global__ void scan_add(int* __restrict__ row_ptr, const int* __restrict__ csums,
                         int n, int E) {
    int idx = blockIdx.x * BLK + threadIdx.x;
    if (idx < n) row_ptr[idx] += csums[idx >> 10];
    if (idx == 0) row_ptr[n] = E;
}

// ---------- scatter edges into dst-grouped order ----------
__global__ void scatter_csr(const int* __restrict__ src, const int* __restrict__ dst,
                            const int* __restrict__ row_ptr, int* __restrict__ wcnt,
                            int* __restrict__ csr, int E) {
    int e = blockIdx.x * BLK + threadIdx.x;
    if (e < E) {
        int d = dst[e];
        int p = row_ptr[d] + atomicAdd(&wcnt[d], 1);
        csr[p] = src[e];
    }
}

// ---------- GEMM: hs = (X @ W) * d_inv[row] ----------
// 64 rows x 64 cols per block (cols padded to 64). Xt transposed in LDS so
// both operands are ds_read_b128. Unroll capped at 4 -> no VGPR spill.
template<int K, int NOUT>
__global__ __launch_bounds__(256) void gemm_scale(
    const float* __restrict__ X, const float* __restrict__ W,
    const float* __restrict__ d_inv, float* __restrict__ hs, int M)
{
    __shared__ float Wl[K * 64];
    __shared__ float Xt[16][68];          // [k within block][row], stride 68: b128-aligned, 2-way max

    int t = threadIdx.x;
    for (int idx = t; idx < K * 64; idx += 256) {
        int k = idx >> 6, c = idx & 63;
        Wl[idx] = (c < NOUT) ? W[k * NOUT + c] : 0.0f;
    }

    int row0 = blockIdx.x * 64;
    int tr = t >> 4, tc = t & 15;         // 16x16 threads, each 4x4 outputs
    int lr = t >> 2, lq = t & 3;          // loader: 64 rows x 4 k-quads
    float a[4][4] = {};

    for (int k0 = 0; k0 < K; k0 += 16) {
        __syncthreads();                  // prev compute done (iter0: Wl ready)
        int grow = row0 + lr;
        float4 xv = make_float4(0.f, 0.f, 0.f, 0.f);
        if (grow < M) xv = *(const float4*)(X + (size_t)grow * K + k0 + lq * 4);
        Xt[lq * 4 + 0][lr] = xv.x; Xt[lq * 4 + 1][lr] = xv.y;
        Xt[lq * 4 + 2][lr] = xv.z; Xt[lq * 4 + 3][lr] = xv.w;
        __syncthreads();

#pragma unroll 4
        for (int kk = 0; kk < 16; ++kk) {
            float4 xr = *(const float4*)(&Xt[kk][tr * 4]);
            float4 wr = *(const float4*)(&Wl[(k0 + kk) * 64 + tc * 4]);
            const float xs[4] = {xr.x, xr.y, xr.z, xr.w};
            const float wsr[4] = {wr.x, wr.y, wr.z, wr.w};
#pragma unroll
            for (int i = 0; i < 4; ++i)
#pragma unroll
                for (int j = 0; j < 4; ++j)
                    a[i][j] += xs[i] * wsr[j];
        }
    }

#pragma unroll
    for (int i = 0; i < 4; ++i) {
        int r = row0 + tr * 4 + i;
        if (r < M) {
            float s = d_inv[r];
            int c = tc * 4;
            if (c < NOUT) {               // NOUT multiple of 4; float4-aligned store
                float4 v = make_float4(a[i][0] * s, a[i][1] * s, a[i][2] * s, a[i][3] * s);
                *(float4*)(hs + (size_t)r * NOUT + c) = v;
            }
        }
    }
}

// ---------- fused aggregate + epilogue ----------
// One wave per node. lane = g*16+q: g = edge subgroup (4 edges in flight),
// q = dim quarter (float4). Cross-group reduce via shfl_xor(16,32).
template<int D, bool RELU>
__global__ __launch_bounds__(256) void agg_fused(
    const float* __restrict__ hs, const int* __restrict__ row_ptr,
    const int* __restrict__ csr, const float* __restrict__ dinv,
    const float* __restrict__ b, float* __restrict__ out, int N)
{
    constexpr int Q = D / 4;              // active dim quarters (16 or 10)
    int wave = (blockIdx.x * 256 + threadIdx.x) >> 6;
    int lane = threadIdx.x & 63;
    if (wave >= N) return;
    int i = wave;
    int g = lane >> 4, q = lane & 15;
    bool qa = (q < Q);

    int beg = row_ptr[i], end = row_ptr[i + 1];
    float4 acc = make_float4(0.f, 0.f, 0.f, 0.f);

    for (int c = beg; c < end; c += 64) {
        int m = end - c; if (m > 64) m = 64;
        int s_l = (c + lane < end) ? csr[c + lane] : 0;    // coalesced src prefetch
        int nIter = (m + 3) >> 2;
        for (int k = 0; k < nIter; ++k) {
            int ei = k * 4 + g;
            int s = __shfl(s_l, ei, 64);
            if (ei < m && qa) {
                const float4 v = *(const float4*)(hs + (size_t)s * D + q * 4);
                acc.x += v.x; acc.y += v.y; acc.z += v.z; acc.w += v.w;
            }
        }
    }

    // reduce the 4 edge subgroups (lanes l, l^16, l^32, l^48)
#pragma unroll
    for (int off = 16; off < 64; off <<= 1) {
        acc.x += __shfl_xor(acc.x, off, 64);
        acc.y += __shfl_xor(acc.y, off, 64);
        acc.z += __shfl_xor(acc.z, off, 64);
        acc.w += __shfl_xor(acc.w, off, 64);
    }

    if (g == 0 && qa) {
        const float4 self = *(const float4*)(hs + (size_t)i * D + q * 4);
        const float4 bv   = *(const float4*)(b + q * 4);
        float di = dinv[i];
        float4 v;
        v.x = di * (acc.x + self.x) + bv.x;
        v.y = di * (acc.y + self.y) + bv.y;
        v.z = di * (acc.z + self.z) + bv.z;
        v.w = di * (acc.w + self.w) + bv.w;
        if (RELU) {
            v.x = fmaxf(v.x, 0.f); v.y = fmaxf(v.y, 0.f);
            v.z = fmaxf(v.z, 0.f); v.w = fmaxf(v.w, 0.f);
        }
        *(float4*)(out + (size_t)i * D + q * 4) = v;
    }
}

extern "C" void kernel_launch(void* const* d_in, const int* in_sizes, int n_in,
                              void* d_out, int out_size, void* d_ws, size_t ws_size,
                              hipStream_t stream) {
    const float* x   = (const float*)d_in[0];
    const int*   ei  = (const int*)  d_in[1];
    const float* W1  = (const float*)d_in[2];
    const float* bb1 = (const float*)d_in[3];
    const float* W2  = (const float*)d_in[4];
    const float* bb2 = (const float*)d_in[5];
    const float* W3  = (const float*)d_in[6];
    const float* bb3 = (const float*)d_in[7];
    float* out = (float*)d_out;

    const int N = in_sizes[0] / 128;      // 100000
    const int E = in_sizes[1] / 2;        // 1600000
    const int* src = ei;
    const int* dst = ei + E;

    // workspace layout (4-byte units)
    float* ws = (float*)d_ws;
    const size_t NP  = ((size_t)N + 255) & ~255ull;
    const size_t N64 = (size_t)N * 64;
    float* dinv = ws;                        // NP
    float* bufH = ws + NP;                   // N*64  (hs)
    float* bufO = bufH + N64;                // N*64  (activations)
    int*   row_ptr = (int*)(bufO + N64);     // N+1
    int*   cnt     = row_ptr + (N + 1);      // N
    int*   csums   = cnt + N;                // 256
    int*   csr     = csums + 256;            // E

    dim3 blk(BLK);
    int gN = (N + BLK - 1) / BLK;
    int gE = (E + BLK - 1) / BLK;
    int gRows = (N + 63) / 64;
    int gWave = (N * 64 + BLK - 1) / BLK;    // one wave per node
    int nChunks = (N + 1023) / 1024;

    // ---- CSR build + degrees ----
    zero_int<<<gN, blk, 0, stream>>>(cnt, N);
    hist_dst<<<gE, blk, 0, stream>>>(dst, cnt, E);
    dinv_from_cnt<<<gN, blk, 0, stream>>>(cnt, dinv, N);
    scan_chunks<<<nChunks, blk, 0, stream>>>(cnt, row_ptr, csums, N);
    scan_sums<<<1, blk, 0, stream>>>(csums, nChunks);
    scan_add<<<gN, blk, 0, stream>>>(row_ptr, csums, N, E);
    zero_int<<<gN, blk, 0, stream>>>(cnt, N);
    scatter_csr<<<gE, blk, 0, stream>>>(src, dst, row_ptr, cnt, csr, E);

    // ---- layer 1: 128 -> 64, relu ----
    gemm_scale<128, 64><<<gRows, blk, 0, stream>>>(x, W1, dinv, bufH, N);
    agg_fused<64, true><<<gWave, blk, 0, stream>>>(bufH, row_ptr, csr, dinv, bb1, bufO, N);

    // ---- layer 2: 64 -> 64, relu ----
    gemm_scale<64, 64><<<gRows, blk, 0, stream>>>(bufO, W2, dinv, bufH, N);
    agg_fused<64, true><<<gWave, blk, 0, stream>>>(bufH, row_ptr, csr, dinv, bb2, bufO, N);

    // ---- layer 3: 64 -> 40, no relu ----
    gemm_scale<64, 40><<<gRows, blk, 0, stream>>>(bufO, W3, dinv, bufH, N);
    agg_fused<40, false><<<gWave, blk, 0, stream>>>(bufH, row_ptr, csr, dinv, bb3, out, N);
}